// Round 13
// baseline (67.367 us; speedup 1.0000x reference)
//
#include <hip/hip_runtime.h>
#include <vector>
#include <cmath>
#include <cstdint>

// ---------------------------------------------------------------------------
// Sparse Clebsch-Gordan tensor product, LMAX=5, TAUS=16, BATCH=256.
//
// R13 = R10 exactly (best so far, 57.6 us), single change: output stores are
// NONTEMPORAL (nt flag -> streaming L2 eviction). Tests whether the L2
// dirty-line path is what caps compute+store kernels at ~4.2 TB/s while the
// pure-store fill hits 6.9 TB/s on the same buffer.
// ---------------------------------------------------------------------------

#define LMAXV 5
#define NTAU 16

static const int CUMT[7] = {0, 16, 64, 144, 256, 400, 576};

constexpr int F4_ROWS  = 288;            // batch's F as f32x4
constexpr int NBATCH   = 256;
constexpr int F4_PER_B = 457 * 128;      // float4 per batch
constexpr int BLK      = 256;
constexpr int NCHUNK   = 8;              // 457 = 7*57 + 58
constexpr int NCOEF    = 2211;
constexpr int MAXJC    = 58;

typedef float f32x4 __attribute__((ext_vector_type(4)));

// ------------------------- host-side CG table build ------------------------

static double factd(int n) { double r = 1.0; for (int i = 2; i <= n; ++i) r *= (double)i; return r; }

static double cg_coef(int j1, int m1, int j2, int m2, int j, int m) {
    if (m1 + m2 != m) return 0.0;
    double pref = std::sqrt((2.0 * j + 1.0) * factd(j + j1 - j2) * factd(j - j1 + j2) *
                            factd(j1 + j2 - j) / factd(j1 + j2 + j + 1));
    pref *= std::sqrt(factd(j + m) * factd(j - m) * factd(j1 - m1) * factd(j1 + m1) *
                      factd(j2 - m2) * factd(j2 + m2));
    int kmin = std::max(0, std::max(j2 - j - m1, j1 + m2 - j));
    int kmax = std::min(j1 + j2 - j, std::min(j1 - m1, j2 + m2));
    double s = 0.0;
    for (int k = kmin; k <= kmax; ++k) {
        s += ((k & 1) ? -1.0 : 1.0) /
             (factd(k) * factd(j1 + j2 - j - k) * factd(j1 - m1 - k) * factd(j2 + m2 - k) *
              factd(j - j2 + m1 + k) * factd(j - j1 - m2 + k));
    }
    return pref * s;
}

struct Tables { std::vector<int4> jobs; std::vector<float> coeffs; };

static const Tables& get_tables() {
    static Tables t = []() {
        Tables t;
        for (int l = 0; l <= LMAXV; ++l) {
            for (int m_idx = 0; m_idx < 2 * l + 1; ++m_idx) {
                int m = m_idx - l;
                for (int l1 = 0; l1 <= LMAXV; ++l1) {
                    for (int l2 = l1; l2 <= LMAXV; ++l2) {
                        if (!(std::abs(l1 - l2) <= l && l <= l1 + l2)) continue;
                        int lo = std::max(-l1, m - l2), hi = std::min(l1, m + l2);
                        int4 jb;
                        // byte offset into sF (f32x4 elems, 16B each) of term k=0
                        jb.x = (CUMT[l1] / 2 + (lo + l1) * 8) * 16;      // a
                        jb.y = (CUMT[l2] / 2 + (m - lo + l2) * 8) * 16;  // v
                        jb.z = hi - lo + 1;                              // count <= 11
                        jb.w = (int)t.coeffs.size();                     // coeff offset
                        for (int m1 = lo; m1 <= hi; ++m1)
                            t.coeffs.push_back((float)cg_coef(l1, m1, l2, m - m1, l, m));
                        t.jobs.push_back(jb);
                    }
                }
            }
        }
        return t;
    }();
    return t;
}

// --------------------------------- kernel ----------------------------------

#define KBODY(N)                                                              \
    {                                                                         \
        f32x4 a[N], v[N]; float cc[N];                                        \
        _Pragma("unroll")                                                     \
        for (int k = 0; k < N; ++k) {                                         \
            a[k]  = *(const f32x4*)(sFb + ax + k * 128);                      \
            v[k]  = *(const f32x4*)(sFb + vy - k * 128);                      \
            cc[k] = sC[coff + k];                                             \
        }                                                                     \
        _Pragma("unroll")                                                     \
        for (int k = 0; k < N; ++k) {                                         \
            r00 = fmaf(cc[k], a[k].x * v[k].x - a[k].y * v[k].y, r00);        \
            i00 = fmaf(cc[k], a[k].x * v[k].y + a[k].y * v[k].x, i00);        \
            r01 = fmaf(cc[k], a[k].x * v[k].z - a[k].y * v[k].w, r01);        \
            i01 = fmaf(cc[k], a[k].x * v[k].w + a[k].y * v[k].z, i01);        \
            r10 = fmaf(cc[k], a[k].z * v[k].x - a[k].w * v[k].y, r10);        \
            i10 = fmaf(cc[k], a[k].z * v[k].y + a[k].w * v[k].x, i10);        \
            r11 = fmaf(cc[k], a[k].z * v[k].z - a[k].w * v[k].w, r11);        \
            i11 = fmaf(cc[k], a[k].z * v[k].w + a[k].w * v[k].z, i11);        \
        }                                                                     \
    }

__global__ __launch_bounds__(256) void cg_tp_kernel(
    const f32x4* __restrict__ Fs, f32x4* __restrict__ out,
    const int4* __restrict__ jobs, const float* __restrict__ coeffs)
{
    __shared__ f32x4 sF[F4_ROWS];        // batch's F, natural layout
    __shared__ float sC[NCOEF];
    __shared__ int4  sJ[MAXJC];

    const int tid   = threadIdx.x;
    const int batch = blockIdx.x >> 3;          // batch-major grid
    const int chunk = blockIdx.x & (NCHUNK - 1);
    const int jbase = chunk * 57;
    const int jcnt  = (chunk == NCHUNK - 1) ? 58 : 57;

    // ---- stage: F (4.6 KB direct copy), coeffs, chunk jobs ----
    {
        const f32x4* __restrict__ Fb4 = Fs + (size_t)batch * F4_ROWS;
        for (int t = tid; t < F4_ROWS; t += BLK) sF[t] = Fb4[t];
        for (int t = tid; t < NCOEF;   t += BLK) sC[t] = coeffs[t];
        for (int t = tid; t < jcnt;    t += BLK) sJ[t] = jobs[jbase + t];
    }
    __syncthreads();

    const int wv   = tid >> 6;          // wave 0..3: handles jobs wv, wv+4, ...
    const int lane = tid & 63;
    const int ip   = lane >> 3;         // i-pair 0..7
    const int jp   = lane & 7;          // j-pair 0..7
    const char* __restrict__ sFb = (const char*)sF;

    f32x4* __restrict__ outb =
        out + (size_t)batch * F4_PER_B + (size_t)jbase * 128;

    for (int jj = wv; jj < jcnt; jj += 4) {
        const int4 jbv = sJ[jj];
        const int ax   = __builtin_amdgcn_readfirstlane(jbv.x) + ip * 16;
        const int vy   = __builtin_amdgcn_readfirstlane(jbv.y) + jp * 16;
        const int cnt  = __builtin_amdgcn_readfirstlane(jbv.z);
        const int coff = __builtin_amdgcn_readfirstlane(jbv.w);

        float r00 = 0.f, i00 = 0.f, r01 = 0.f, i01 = 0.f;
        float r10 = 0.f, i10 = 0.f, r11 = 0.f, i11 = 0.f;

        switch (cnt) {
            case 1:  KBODY(1)  break;
            case 2:  KBODY(2)  break;
            case 3:  KBODY(3)  break;
            case 4:  KBODY(4)  break;
            case 5:  KBODY(5)  break;
            case 6:  KBODY(6)  break;
            case 7:  KBODY(7)  break;
            case 8:  KBODY(8)  break;
            case 9:  KBODY(9)  break;
            case 10: KBODY(10) break;
            default: KBODY(11) break;
        }

        // rows i=2ip and 2ip+1, columns 2jp..2jp+1 — NONTEMPORAL (the A/B)
        f32x4 s0; s0.x = r00; s0.y = i00; s0.z = r01; s0.w = i01;
        f32x4 s1; s1.x = r10; s1.y = i10; s1.z = r11; s1.w = i11;
        f32x4* __restrict__ po = outb + (size_t)jj * 128 + ip * 16 + jp;
        __builtin_nontemporal_store(s0, po);       // i = 2ip
        __builtin_nontemporal_store(s1, po + 8);   // i = 2ip+1
    }
}

// ------------------------------ entry point --------------------------------

extern "C" void kernel_launch(void* const* d_in, const int* in_sizes, int n_in,
                              void* d_out, int out_size, void* d_ws, size_t ws_size,
                              hipStream_t stream) {
    const Tables& t = get_tables();

    char*  ws       = (char*)d_ws;
    int4*  d_jobs   = (int4*)ws;
    size_t jbytes   = t.jobs.size() * sizeof(int4);
    size_t coff     = (jbytes + 255) & ~(size_t)255;
    float* d_coeffs = (float*)(ws + coff);

    hipMemcpyAsync(d_jobs, t.jobs.data(), jbytes, hipMemcpyHostToDevice, stream);
    hipMemcpyAsync(d_coeffs, t.coeffs.data(), t.coeffs.size() * sizeof(float),
                   hipMemcpyHostToDevice, stream);

    const f32x4* Fs  = (const f32x4*)d_in[0];
    f32x4*       out = (f32x4*)d_out;

    cg_tp_kernel<<<NBATCH * NCHUNK, BLK, 0, stream>>>(Fs, out, d_jobs, d_coeffs);
}

// Round 14
// 52.010 us; speedup vs baseline: 1.2953x; 1.2953x over previous
//
#include <hip/hip_runtime.h>
#include <vector>
#include <cmath>
#include <cstdint>

// ---------------------------------------------------------------------------
// Sparse Clebsch-Gordan tensor product, LMAX=5, TAUS=16, BATCH=256.
//
// R14 = R10 (best: 57.6 us) + serial-chain attack:
//   - job metadata moved from LDS to SMEM s_load (wave-uniform index) and
//     PREFETCHED one job ahead -> metadata latency hides under current FMAs
//   - per-job coeffs padded to 4-aligned starts, read as 1-3 broadcast
//     ds_read_b128 quads instead of cnt scalar b32 reads
//   - compute micro-tile, operand LDS layout, grid, and the regular f32x4
//     store schedule are bit-identical to R10 (NT proven worse in R13).
// ---------------------------------------------------------------------------

#define LMAXV 5
#define NTAU 16

static const int CUMT[7] = {0, 16, 64, 144, 256, 400, 576};

constexpr int F4_ROWS  = 288;            // batch's F as f32x4
constexpr int NBATCH   = 256;
constexpr int F4_PER_B = 457 * 128;      // float4 per batch
constexpr int BLK      = 256;
constexpr int NCHUNK   = 8;              // 457 = 7*57 + 58
constexpr int NJOBS    = 457;
constexpr int MAXC4    = 1400;           // padded coeff quads (worst 457*3)

typedef float f32x4 __attribute__((ext_vector_type(4)));

// ------------------------- host-side CG table build ------------------------

static double factd(int n) { double r = 1.0; for (int i = 2; i <= n; ++i) r *= (double)i; return r; }

static double cg_coef(int j1, int m1, int j2, int m2, int j, int m) {
    if (m1 + m2 != m) return 0.0;
    double pref = std::sqrt((2.0 * j + 1.0) * factd(j + j1 - j2) * factd(j - j1 + j2) *
                            factd(j1 + j2 - j) / factd(j1 + j2 + j + 1));
    pref *= std::sqrt(factd(j + m) * factd(j - m) * factd(j1 - m1) * factd(j1 + m1) *
                      factd(j2 - m2) * factd(j2 + m2));
    int kmin = std::max(0, std::max(j2 - j - m1, j1 + m2 - j));
    int kmax = std::min(j1 + j2 - j, std::min(j1 - m1, j2 + m2));
    double s = 0.0;
    for (int k = kmin; k <= kmax; ++k) {
        s += ((k & 1) ? -1.0 : 1.0) /
             (factd(k) * factd(j1 + j2 - j - k) * factd(j1 - m1 - k) * factd(j2 + m2 - k) *
              factd(j - j2 + m1 + k) * factd(j - j1 - m2 + k));
    }
    return pref * s;
}

struct Tables { std::vector<int4> jobs; std::vector<float> coeffs; };  // coeffs padded

static const Tables& get_tables() {
    static Tables t = []() {
        Tables t;
        for (int l = 0; l <= LMAXV; ++l) {
            for (int m_idx = 0; m_idx < 2 * l + 1; ++m_idx) {
                int m = m_idx - l;
                for (int l1 = 0; l1 <= LMAXV; ++l1) {
                    for (int l2 = l1; l2 <= LMAXV; ++l2) {
                        if (!(std::abs(l1 - l2) <= l && l <= l1 + l2)) continue;
                        int lo = std::max(-l1, m - l2), hi = std::min(l1, m + l2);
                        // pad coeff array so this job's run starts 4-aligned
                        while (t.coeffs.size() & 3) t.coeffs.push_back(0.0f);
                        int4 jb;
                        jb.x = (CUMT[l1] / 2 + (lo + l1) * 8) * 16;      // a byte off, k=0
                        jb.y = (CUMT[l2] / 2 + (m - lo + l2) * 8) * 16;  // v byte off, k=0
                        jb.z = hi - lo + 1;                              // cnt <= 11
                        jb.w = (int)(t.coeffs.size() >> 2);              // coeff QUAD off
                        for (int m1 = lo; m1 <= hi; ++m1)
                            t.coeffs.push_back((float)cg_coef(l1, m1, l2, m - m1, l, m));
                        t.jobs.push_back(jb);
                    }
                }
            }
        }
        while (t.coeffs.size() & 3) t.coeffs.push_back(0.0f);
        return t;
    }();
    return t;
}

// --------------------------------- kernel ----------------------------------

#define KBODY(N)                                                              \
    {                                                                         \
        constexpr int Q = ((N) + 3) / 4;                                      \
        f32x4 cq[Q];                                                          \
        _Pragma("unroll")                                                     \
        for (int q = 0; q < Q; ++q) cq[q] = sC4[coff4 + q];                   \
        f32x4 a[N], v[N];                                                     \
        _Pragma("unroll")                                                     \
        for (int k = 0; k < N; ++k) {                                         \
            a[k] = *(const f32x4*)(sFb + ax + k * 128);                       \
            v[k] = *(const f32x4*)(sFb + vy - k * 128);                       \
        }                                                                     \
        _Pragma("unroll")                                                     \
        for (int k = 0; k < N; ++k) {                                         \
            const float c = cq[k >> 2][k & 3];                                \
            r00 = fmaf(c, a[k].x * v[k].x - a[k].y * v[k].y, r00);            \
            i00 = fmaf(c, a[k].x * v[k].y + a[k].y * v[k].x, i00);            \
            r01 = fmaf(c, a[k].x * v[k].z - a[k].y * v[k].w, r01);            \
            i01 = fmaf(c, a[k].x * v[k].w + a[k].y * v[k].z, i01);            \
            r10 = fmaf(c, a[k].z * v[k].x - a[k].w * v[k].y, r10);            \
            i10 = fmaf(c, a[k].z * v[k].y + a[k].w * v[k].x, i10);            \
            r11 = fmaf(c, a[k].z * v[k].z - a[k].w * v[k].w, r11);            \
            i11 = fmaf(c, a[k].z * v[k].w + a[k].w * v[k].z, i11);            \
        }                                                                     \
    }

__global__ __launch_bounds__(256) void cg_tp_kernel(
    const f32x4* __restrict__ Fs, f32x4* __restrict__ out,
    const int4* __restrict__ jobs, const f32x4* __restrict__ coeffs4,
    int ncoef4)
{
    __shared__ f32x4 sF[F4_ROWS];        // batch's F, natural layout (4.6 KB)
    __shared__ f32x4 sC4[MAXC4];         // padded coeff quads

    const int tid   = threadIdx.x;
    const int batch = blockIdx.x >> 3;          // batch-major grid
    const int chunk = blockIdx.x & (NCHUNK - 1);
    const int jbase = chunk * 57;
    const int jcnt  = (chunk == NCHUNK - 1) ? 58 : 57;

    // ---- stage: F + padded coeffs ----
    {
        const f32x4* __restrict__ Fb4 = Fs + (size_t)batch * F4_ROWS;
        for (int t = tid; t < F4_ROWS; t += BLK) sF[t] = Fb4[t];
        for (int t = tid; t < ncoef4;  t += BLK) sC4[t] = coeffs4[t];
    }
    __syncthreads();

    // wave-uniform (forced scalar) job cursor -> jobs[] reads become s_load
    const int wv   = __builtin_amdgcn_readfirstlane(tid >> 6);   // 0..3
    const int lane = tid & 63;
    const int ip   = lane >> 3;         // i-pair 0..7
    const int jp   = lane & 7;          // j-pair 0..7
    const char* __restrict__ sFb = (const char*)sF;

    f32x4* __restrict__ outb =
        out + (size_t)batch * F4_PER_B + (size_t)jbase * 128;

    int4 meta = jobs[jbase + wv];       // prefetch first job's metadata
    for (int jj = wv; jj < jcnt; jj += 4) {
        const int4 cur = meta;
        const int  jn  = jj + 4;
        if (jn < jcnt) meta = jobs[jbase + jn];   // prefetch next (scalar)

        const int ax    = __builtin_amdgcn_readfirstlane(cur.x) + ip * 16;
        const int vy    = __builtin_amdgcn_readfirstlane(cur.y) + jp * 16;
        const int cnt   = __builtin_amdgcn_readfirstlane(cur.z);
        const int coff4 = __builtin_amdgcn_readfirstlane(cur.w);

        float r00 = 0.f, i00 = 0.f, r01 = 0.f, i01 = 0.f;
        float r10 = 0.f, i10 = 0.f, r11 = 0.f, i11 = 0.f;

        switch (cnt) {
            case 1:  KBODY(1)  break;
            case 2:  KBODY(2)  break;
            case 3:  KBODY(3)  break;
            case 4:  KBODY(4)  break;
            case 5:  KBODY(5)  break;
            case 6:  KBODY(6)  break;
            case 7:  KBODY(7)  break;
            case 8:  KBODY(8)  break;
            case 9:  KBODY(9)  break;
            case 10: KBODY(10) break;
            default: KBODY(11) break;
        }

        // rows i=2ip and 2ip+1, columns 2jp..2jp+1 — regular stores (R13: NT worse)
        f32x4 s0; s0.x = r00; s0.y = i00; s0.z = r01; s0.w = i01;
        f32x4 s1; s1.x = r10; s1.y = i10; s1.z = r11; s1.w = i11;
        f32x4* __restrict__ po = outb + (size_t)jj * 128 + ip * 16 + jp;
        po[0] = s0;          // i = 2ip
        po[8] = s1;          // i = 2ip+1
    }
}

// ------------------------------ entry point --------------------------------

extern "C" void kernel_launch(void* const* d_in, const int* in_sizes, int n_in,
                              void* d_out, int out_size, void* d_ws, size_t ws_size,
                              hipStream_t stream) {
    const Tables& t = get_tables();

    char*  ws       = (char*)d_ws;
    int4*  d_jobs   = (int4*)ws;
    size_t jbytes   = t.jobs.size() * sizeof(int4);
    size_t coff     = (jbytes + 255) & ~(size_t)255;
    float* d_coeffs = (float*)(ws + coff);

    hipMemcpyAsync(d_jobs, t.jobs.data(), jbytes, hipMemcpyHostToDevice, stream);
    hipMemcpyAsync(d_coeffs, t.coeffs.data(), t.coeffs.size() * sizeof(float),
                   hipMemcpyHostToDevice, stream);

    const f32x4* Fs  = (const f32x4*)d_in[0];
    f32x4*       out = (f32x4*)d_out;
    const int ncoef4 = (int)(t.coeffs.size() >> 2);

    cg_tp_kernel<<<NBATCH * NCHUNK, BLK, 0, stream>>>(
        Fs, out, d_jobs, (const f32x4*)d_coeffs, ncoef4);
}

// Round 15
// 52.005 us; speedup vs baseline: 1.2954x; 1.0001x over previous
//
#include <hip/hip_runtime.h>
#include <vector>
#include <cmath>
#include <cstdint>
#include <cassert>

// ---------------------------------------------------------------------------
// Sparse Clebsch-Gordan tensor product, LMAX=5, TAUS=16, BATCH=256.
//
// R15 = R14 (52.0 us) with ONE change: MAXC4 1400 -> 896 quads, shrinking
// per-block LDS 27 KB -> 18.9 KB so 8 blocks/CU fit (thread limit) instead
// of 5. +60% resident waves to hide the per-job lgkmcnt stalls that keep us
// 17 us above the ~35 us store-drain floor. Everything else bit-identical:
// scalar prefetched job metadata, b128 coeff quads, 2x2 micro-tile,
// conflict-free LDS operand reads, regular f32x4 stores (NT worse, R13).
// ---------------------------------------------------------------------------

#define LMAXV 5
#define NTAU 16

static const int CUMT[7] = {0, 16, 64, 144, 256, 400, 576};

constexpr int F4_ROWS  = 288;            // batch's F as f32x4
constexpr int NBATCH   = 256;
constexpr int F4_PER_B = 457 * 128;      // float4 per batch
constexpr int BLK      = 256;
constexpr int NCHUNK   = 8;              // 457 = 7*57 + 58
constexpr int NJOBS    = 457;
constexpr int MAXC4    = 896;            // tight: 2211 + <=3 pad/job = <=3582 f32

typedef float f32x4 __attribute__((ext_vector_type(4)));

// ------------------------- host-side CG table build ------------------------

static double factd(int n) { double r = 1.0; for (int i = 2; i <= n; ++i) r *= (double)i; return r; }

static double cg_coef(int j1, int m1, int j2, int m2, int j, int m) {
    if (m1 + m2 != m) return 0.0;
    double pref = std::sqrt((2.0 * j + 1.0) * factd(j + j1 - j2) * factd(j - j1 + j2) *
                            factd(j1 + j2 - j) / factd(j1 + j2 + j + 1));
    pref *= std::sqrt(factd(j + m) * factd(j - m) * factd(j1 - m1) * factd(j1 + m1) *
                      factd(j2 - m2) * factd(j2 + m2));
    int kmin = std::max(0, std::max(j2 - j - m1, j1 + m2 - j));
    int kmax = std::min(j1 + j2 - j, std::min(j1 - m1, j2 + m2));
    double s = 0.0;
    for (int k = kmin; k <= kmax; ++k) {
        s += ((k & 1) ? -1.0 : 1.0) /
             (factd(k) * factd(j1 + j2 - j - k) * factd(j1 - m1 - k) * factd(j2 + m2 - k) *
              factd(j - j2 + m1 + k) * factd(j - j1 - m2 + k));
    }
    return pref * s;
}

struct Tables { std::vector<int4> jobs; std::vector<float> coeffs; };  // coeffs padded

static const Tables& get_tables() {
    static Tables t = []() {
        Tables t;
        for (int l = 0; l <= LMAXV; ++l) {
            for (int m_idx = 0; m_idx < 2 * l + 1; ++m_idx) {
                int m = m_idx - l;
                for (int l1 = 0; l1 <= LMAXV; ++l1) {
                    for (int l2 = l1; l2 <= LMAXV; ++l2) {
                        if (!(std::abs(l1 - l2) <= l && l <= l1 + l2)) continue;
                        int lo = std::max(-l1, m - l2), hi = std::min(l1, m + l2);
                        // pad coeff array so this job's run starts 4-aligned
                        while (t.coeffs.size() & 3) t.coeffs.push_back(0.0f);
                        int4 jb;
                        jb.x = (CUMT[l1] / 2 + (lo + l1) * 8) * 16;      // a byte off, k=0
                        jb.y = (CUMT[l2] / 2 + (m - lo + l2) * 8) * 16;  // v byte off, k=0
                        jb.z = hi - lo + 1;                              // cnt <= 11
                        jb.w = (int)(t.coeffs.size() >> 2);              // coeff QUAD off
                        for (int m1 = lo; m1 <= hi; ++m1)
                            t.coeffs.push_back((float)cg_coef(l1, m1, l2, m - m1, l, m));
                        t.jobs.push_back(jb);
                    }
                }
            }
        }
        while (t.coeffs.size() & 3) t.coeffs.push_back(0.0f);
        assert((int)(t.coeffs.size() >> 2) <= MAXC4);
        return t;
    }();
    return t;
}

// --------------------------------- kernel ----------------------------------

#define KBODY(N)                                                              \
    {                                                                         \
        constexpr int Q = ((N) + 3) / 4;                                      \
        f32x4 cq[Q];                                                          \
        _Pragma("unroll")                                                     \
        for (int q = 0; q < Q; ++q) cq[q] = sC4[coff4 + q];                   \
        f32x4 a[N], v[N];                                                     \
        _Pragma("unroll")                                                     \
        for (int k = 0; k < N; ++k) {                                         \
            a[k] = *(const f32x4*)(sFb + ax + k * 128);                       \
            v[k] = *(const f32x4*)(sFb + vy - k * 128);                       \
        }                                                                     \
        _Pragma("unroll")                                                     \
        for (int k = 0; k < N; ++k) {                                         \
            const float c = cq[k >> 2][k & 3];                                \
            r00 = fmaf(c, a[k].x * v[k].x - a[k].y * v[k].y, r00);            \
            i00 = fmaf(c, a[k].x * v[k].y + a[k].y * v[k].x, i00);            \
            r01 = fmaf(c, a[k].x * v[k].z - a[k].y * v[k].w, r01);            \
            i01 = fmaf(c, a[k].x * v[k].w + a[k].y * v[k].z, i01);            \
            r10 = fmaf(c, a[k].z * v[k].x - a[k].w * v[k].y, r10);            \
            i10 = fmaf(c, a[k].z * v[k].y + a[k].w * v[k].x, i10);            \
            r11 = fmaf(c, a[k].z * v[k].z - a[k].w * v[k].w, r11);            \
            i11 = fmaf(c, a[k].z * v[k].w + a[k].w * v[k].z, i11);            \
        }                                                                     \
    }

__global__ __launch_bounds__(256) void cg_tp_kernel(
    const f32x4* __restrict__ Fs, f32x4* __restrict__ out,
    const int4* __restrict__ jobs, const f32x4* __restrict__ coeffs4,
    int ncoef4)
{
    __shared__ f32x4 sF[F4_ROWS];        // batch's F, natural layout (4.6 KB)
    __shared__ f32x4 sC4[MAXC4];         // padded coeff quads (14.3 KB)

    const int tid   = threadIdx.x;
    const int batch = blockIdx.x >> 3;          // batch-major grid
    const int chunk = blockIdx.x & (NCHUNK - 1);
    const int jbase = chunk * 57;
    const int jcnt  = (chunk == NCHUNK - 1) ? 58 : 57;

    // ---- stage: F + padded coeffs ----
    {
        const f32x4* __restrict__ Fb4 = Fs + (size_t)batch * F4_ROWS;
        for (int t = tid; t < F4_ROWS; t += BLK) sF[t] = Fb4[t];
        for (int t = tid; t < ncoef4;  t += BLK) sC4[t] = coeffs4[t];
    }
    __syncthreads();

    // wave-uniform (forced scalar) job cursor -> jobs[] reads become s_load
    const int wv   = __builtin_amdgcn_readfirstlane(tid >> 6);   // 0..3
    const int lane = tid & 63;
    const int ip   = lane >> 3;         // i-pair 0..7
    const int jp   = lane & 7;          // j-pair 0..7
    const char* __restrict__ sFb = (const char*)sF;

    f32x4* __restrict__ outb =
        out + (size_t)batch * F4_PER_B + (size_t)jbase * 128;

    int4 meta = jobs[jbase + wv];       // prefetch first job's metadata
    for (int jj = wv; jj < jcnt; jj += 4) {
        const int4 cur = meta;
        const int  jn  = jj + 4;
        if (jn < jcnt) meta = jobs[jbase + jn];   // prefetch next (scalar)

        const int ax    = __builtin_amdgcn_readfirstlane(cur.x) + ip * 16;
        const int vy    = __builtin_amdgcn_readfirstlane(cur.y) + jp * 16;
        const int cnt   = __builtin_amdgcn_readfirstlane(cur.z);
        const int coff4 = __builtin_amdgcn_readfirstlane(cur.w);

        float r00 = 0.f, i00 = 0.f, r01 = 0.f, i01 = 0.f;
        float r10 = 0.f, i10 = 0.f, r11 = 0.f, i11 = 0.f;

        switch (cnt) {
            case 1:  KBODY(1)  break;
            case 2:  KBODY(2)  break;
            case 3:  KBODY(3)  break;
            case 4:  KBODY(4)  break;
            case 5:  KBODY(5)  break;
            case 6:  KBODY(6)  break;
            case 7:  KBODY(7)  break;
            case 8:  KBODY(8)  break;
            case 9:  KBODY(9)  break;
            case 10: KBODY(10) break;
            default: KBODY(11) break;
        }

        // rows i=2ip and 2ip+1, columns 2jp..2jp+1 — regular stores
        f32x4 s0; s0.x = r00; s0.y = i00; s0.z = r01; s0.w = i01;
        f32x4 s1; s1.x = r10; s1.y = i10; s1.z = r11; s1.w = i11;
        f32x4* __restrict__ po = outb + (size_t)jj * 128 + ip * 16 + jp;
        po[0] = s0;          // i = 2ip
        po[8] = s1;          // i = 2ip+1
    }
}

// ------------------------------ entry point --------------------------------

extern "C" void kernel_launch(void* const* d_in, const int* in_sizes, int n_in,
                              void* d_out, int out_size, void* d_ws, size_t ws_size,
                              hipStream_t stream) {
    const Tables& t = get_tables();

    char*  ws       = (char*)d_ws;
    int4*  d_jobs   = (int4*)ws;
    size_t jbytes   = t.jobs.size() * sizeof(int4);
    size_t coff     = (jbytes + 255) & ~(size_t)255;
    float* d_coeffs = (float*)(ws + coff);

    hipMemcpyAsync(d_jobs, t.jobs.data(), jbytes, hipMemcpyHostToDevice, stream);
    hipMemcpyAsync(d_coeffs, t.coeffs.data(), t.coeffs.size() * sizeof(float),
                   hipMemcpyHostToDevice, stream);

    const f32x4* Fs  = (const f32x4*)d_in[0];
    f32x4*       out = (f32x4*)d_out;
    const int ncoef4 = (int)(t.coeffs.size() >> 2);

    cg_tp_kernel<<<NBATCH * NCHUNK, BLK, 0, stream>>>(
        Fs, out, d_jobs, (const f32x4*)d_coeffs, ncoef4);
}